// Round 9
// baseline (1011.487 us; speedup 1.0000x reference)
//
#include <hip/hip_runtime.h>

// Problem constants: B=32, T=256, IN=64, D=128
// Outputs (fp32): h_final[32,128] | y[32,256,128] | jacs[256,32,128,128] | dh_dWh[32,128,128,128]
// out offsets: 0, 4096, 1052672, 135270400  (total 202379264)
//
// Round 9: r8 fused structure + delayed counted-vmcnt flag publication.
// r8's per-16-step __syncthreads drained vmcnt(0) through an LLC congested by
// 224 worker CUs (~4.6 TB/s) -> multi-us stall x16 on the serial scan path.
// Now: publish chunk c at t = 16c+19 with s_waitcnt vmcnt(16). Each step issues
// >=5 vmem insts/wave (1 xw float4 load + 4 stores to distinct buffers), so
// <=16 outstanding => all ops >=4 steps old (incl. chunk c's stores) retired
// to LLC. Waiting on long-retired ops ~ free; publication delay ~3.4 us moot.
// Chunk 15 + ctrl[16] published post-loop behind a full drain.

#define JACOFF 1052672L
#define DHWOFF 135270400L

#define NTICK_JAC   8192u
#define NTICK_TOTAL 10240u   // 8192 jac tiles + 2048 dhdw pairs

typedef __attribute__((ext_vector_type(8))) short frag_ab;   // 8 bf16
typedef __attribute__((ext_vector_type(4))) float frag_cd;   // 4 fp32 (native vec: ok for nt store)

__device__ __forceinline__ short f2bf(float f) {
    unsigned u = __builtin_bit_cast(unsigned, f);
    unsigned r = (u + 0x7fffu + ((u >> 16) & 1u)) >> 16;     // RNE
    return (short)r;
}

__device__ __forceinline__ void wg_barrier() {
    asm volatile("s_waitcnt lgkmcnt(0)\n\ts_barrier" ::: "memory");
}

// Full reduction across a 16-lane DPP row.
__device__ __forceinline__ float row_reduce16(float x) {
    int t;
    t = __builtin_amdgcn_mov_dpp(__builtin_bit_cast(int, x), 0x128, 0xF, 0xF, true);
    x += __builtin_bit_cast(float, t);
    t = __builtin_amdgcn_mov_dpp(__builtin_bit_cast(int, x), 0x124, 0xF, 0xF, true);
    x += __builtin_bit_cast(float, t);
    t = __builtin_amdgcn_mov_dpp(__builtin_bit_cast(int, x), 0x4E, 0xF, 0xF, true);
    x += __builtin_bit_cast(float, t);
    t = __builtin_amdgcn_mov_dpp(__builtin_bit_cast(int, x), 0xB1, 0xF, 0xF, true);
    x += __builtin_bit_cast(float, t);
    return x;
}

// gelu + gelu' with one fast exp (A&S 7.1.26).
__device__ __forceinline__ void gelu_pair(float pre, float& a, float& dval) {
    const float inv_sqrt2   = 0.70710678118654752f;
    const float inv_sqrt2pi = 0.39894228040143268f;
    float ex2 = __expf(-0.5f * pre * pre);
    float az  = fabsf(pre) * inv_sqrt2;
    float t   = 1.0f / (1.0f + 0.3275911f * az);
    float poly = ((((1.061405429f * t - 1.453152027f) * t + 1.421413741f) * t
                   - 0.284496736f) * t + 0.254829592f) * t;
    float erf_abs = 1.0f - poly * ex2;
    float erf_z = (pre < 0.f) ? -erf_abs : erf_abs;
    float cdf = 0.5f * (1.0f + erf_z);
    a = pre * cdf;
    dval = cdf + pre * inv_sqrt2pi * ex2;
}

// ---------- prep: transposes + xw + PT + ctrl zero ----------
__global__ __launch_bounds__(256) void prep_kernel(
    const float* __restrict__ Wh, const float* __restrict__ Wg,
    const float* __restrict__ x, const float* __restrict__ Wx,
    float* __restrict__ whT, float* __restrict__ wgT, float* __restrict__ xw,
    short* __restrict__ PT, unsigned* __restrict__ ctrl)
{
    int blk = blockIdx.x;
    int tid = threadIdx.x;
    if (blk < 128) {
        int idx = blk * 256 + tid;               // 0..32767
        if (idx < 16384) {                       // WhT[i][k] = Wh[k][i]
            int k = idx >> 7, i = idx & 127;
            whT[i * 128 + k] = Wh[idx];
        } else {                                 // WgT[i][k] = Wgate[k][i]
            int r = idx - 16384;
            int k = r >> 7, i = r & 127;
            wgT[i * 128 + k] = Wg[r];
        }
        return;
    }
    if (blk < 4224) {
        // xw path: 2 (b,t) rows per block
        __shared__ float xs[2][64];
        int sub = tid >> 7;
        int bt = (blk - 128) * 2 + sub;
        int i = tid & 127;
        if (i < 64) xs[sub][i] = x[bt * 64 + i];
        __syncthreads();
        float acc = 0.f;
#pragma unroll
        for (int m = 0; m < 64; ++m)
            acc += xs[sub][m] * Wx[m * 128 + i];
        xw[bt * 128 + i] = acc;
        return;
    }
    if (blk < 5248) {
        // PT[col][k] = bf16(Wgate[k][i] * Wh[j][k]), col = i*128+j. 16 cols/block.
        int c = (blk - 4224) * 16 + (tid >> 4);
        int k0 = (tid & 15) * 8;
        int i = c >> 7, j = c & 127;
        short v[8];
#pragma unroll
        for (int m = 0; m < 8; ++m) {
            float wg = Wg[(k0 + m) * 128 + i];
            float wh = Wh[j * 128 + k0 + m];
            v[m] = f2bf(wg * wh);
        }
        *(frag_ab*)(PT + (long)c * 128 + k0) = *(frag_ab*)v;
        return;
    }
    if (tid < 128) ctrl[tid] = 0u;               // flags[0..16], ticket at [64]
}

// ---------- fused scan + jacmm + dhdw (256 blocks x 512 thr, 1 block/CU) ----------
__global__ __launch_bounds__(512, 1) void fused_kernel(
    const float* __restrict__ xw, const float* __restrict__ h0,
    const float* __restrict__ whT, const float* __restrict__ wgT,
    const float* __restrict__ Wgate,
    float* __restrict__ out,
    short* __restrict__ Abf, float* __restrict__ wgv, float* __restrict__ wc,
    float* __restrict__ wdF, float* __restrict__ wuF, float* __restrict__ whF,
    const short* __restrict__ PT, unsigned* __restrict__ ctrl)
{
    const int tid = threadIdx.x;
    __shared__ float hbuf[2][128];
    __shared__ float abuf[128];
    __shared__ float cstage[64 * 132];           // 33.8 KB (stride 132: 2-way = free)
    __shared__ float hs2[2][128], ds2[2][128];
    __shared__ unsigned sh_u;
    // + 52 KB dynamic pad at launch -> ~89 KB total -> exactly 1 block/CU

    if (blockIdx.x < 32) {
        // ================= scan (producer) =================
        const int b = blockIdx.x;
        const int og = tid >> 4;        // 4 outputs: i = og*4+m
        const int kg = tid & 15;        // 8 k-values: k = kg*8..+7
        const int mm = kg & 3;
        const int iw = og * 4 + kg;
        const bool wlane = (kg < 4);

        float wh[4][8], wgc[4][8];
#pragma unroll
        for (int m = 0; m < 4; ++m) {
            const float* whr = whT + (og * 4 + m) * 128 + kg * 8;
            const float* wgr = wgT + (og * 4 + m) * 128 + kg * 8;
            float4 a4 = *(const float4*)(whr);
            float4 b4 = *(const float4*)(whr + 4);
            wh[m][0] = a4.x; wh[m][1] = a4.y; wh[m][2] = a4.z; wh[m][3] = a4.w;
            wh[m][4] = b4.x; wh[m][5] = b4.y; wh[m][6] = b4.z; wh[m][7] = b4.w;
            float4 c4 = *(const float4*)(wgr);
            float4 d4 = *(const float4*)(wgr + 4);
            wgc[m][0] = c4.x; wgc[m][1] = c4.y; wgc[m][2] = c4.z; wgc[m][3] = c4.w;
            wgc[m][4] = d4.x; wgc[m][5] = d4.y; wgc[m][6] = d4.z; wgc[m][7] = d4.w;
        }
        if (wlane) hbuf[0][iw] = h0[b * 128 + iw];
        __syncthreads();

        float4 xwv4 = *(const float4*)(xw + (b * 256 + 0) * 128 + og * 4);
        float4 xw14 = *(const float4*)(xw + (b * 256 + 1) * 128 + og * 4);

        for (int t = 0; t < 256; ++t) {
            int p = t & 1;
            int tn = (t < 254) ? t + 2 : 255;
            float4 xw24 = *(const float4*)(xw + (b * 256 + tn) * 128 + og * 4);

            // phase A
            float h8[8];
            {
                const float* hb = &hbuf[p][kg * 8];
                float4 a4 = *(const float4*)(hb);
                float4 b4 = *(const float4*)(hb + 4);
                h8[0] = a4.x; h8[1] = a4.y; h8[2] = a4.z; h8[3] = a4.w;
                h8[4] = b4.x; h8[5] = b4.y; h8[6] = b4.z; h8[7] = b4.w;
            }
            float s0 = 0.f, s1 = 0.f, s2 = 0.f, s3 = 0.f;
#pragma unroll
            for (int kk = 0; kk < 8; ++kk) {
                s0 += h8[kk] * wh[0][kk];
                s1 += h8[kk] * wh[1][kk];
                s2 += h8[kk] * wh[2][kk];
                s3 += h8[kk] * wh[3][kk];
            }
            s0 = row_reduce16(s0); s1 = row_reduce16(s1);
            s2 = row_reduce16(s2); s3 = row_reduce16(s3);
            float pre = (mm == 0) ? (xwv4.x + s0) : (mm == 1) ? (xwv4.y + s1)
                      : (mm == 2) ? (xwv4.z + s2) : (xwv4.w + s3);
            float a, dval;
            gelu_pair(pre, a, dval);

            long tb = (long)(t * 32 + b) * 128 + iw;
            if (wlane) {
                __hip_atomic_store(&Abf[tb], f2bf(dval), __ATOMIC_RELAXED, __HIP_MEMORY_SCOPE_AGENT);
                abuf[iw] = a;
            }
            wg_barrier();                                      // (1) abuf visible

            // phase B
            float a8[8];
            {
                const float* ab = &abuf[kg * 8];
                float4 a4 = *(const float4*)(ab);
                float4 b4 = *(const float4*)(ab + 4);
                a8[0] = a4.x; a8[1] = a4.y; a8[2] = a4.z; a8[3] = a4.w;
                a8[4] = b4.x; a8[5] = b4.y; a8[6] = b4.z; a8[7] = b4.w;
            }
            float r0 = 0.f, r1 = 0.f, r2 = 0.f, r3 = 0.f;
#pragma unroll
            for (int kk = 0; kk < 8; ++kk) {
                r0 += a8[kk] * wgc[0][kk];
                r1 += a8[kk] * wgc[1][kk];
                r2 += a8[kk] * wgc[2][kk];
                r3 += a8[kk] * wgc[3][kk];
            }
            r0 = row_reduce16(r0); r1 = row_reduce16(r1);
            r2 = row_reduce16(r2); r3 = row_reduce16(r3);
            float r = (mm == 0) ? r0 : (mm == 1) ? r1 : (mm == 2) ? r2 : r3;

            float g = 1.0f / (1.0f + __expf(-r));
            float hp = hbuf[p][og * 4 + mm];
            float c = (hp - 1.0f) * g * (1.0f - g);
            float hn = g * hp + 1.0f - g;
            if (wlane) {
                hbuf[p ^ 1][iw] = hn;
                __hip_atomic_store(&wgv[tb], g, __ATOMIC_RELAXED, __HIP_MEMORY_SCOPE_AGENT);
                __hip_atomic_store(&wc[tb], c, __ATOMIC_RELAXED, __HIP_MEMORY_SCOPE_AGENT);
                out[4096 + (b * 256 + t) * 128 + iw] = hn;     // y
            }
            xwv4 = xw14; xw14 = xw24;

            // Delayed counted-vmcnt publication: at t = 16c+19, all of chunk c's
            // stores are >=4 steps (>=20 vmem insts/wave) old; vmcnt(16) proves
            // they retired to LLC without draining recent traffic.
            if ((t & 15) == 3 && t >= 19) {
                asm volatile("s_waitcnt vmcnt(16)" ::: "memory");
                wg_barrier();                                  // (2) new h visible
                if (tid == 0)
                    __hip_atomic_fetch_add(&ctrl[(t >> 4) - 1], 1u, __ATOMIC_RELAXED, __HIP_MEMORY_SCOPE_AGENT);
            } else {
                wg_barrier();                                  // (2) new h visible
            }
        }

        // full drain once, then publish chunk 15
        __syncthreads();
        if (tid == 0)
            __hip_atomic_fetch_add(&ctrl[15], 1u, __ATOMIC_RELAXED, __HIP_MEMORY_SCOPE_AGENT);

        float hfin = hbuf[0][og * 4 + mm];
        if (wlane) {
            out[b * 128 + iw] = hbuf[0][iw];                   // h_final
            __hip_atomic_store(&whF[b * 128 + iw], hbuf[0][iw], __ATOMIC_RELAXED, __HIP_MEMORY_SCOPE_AGENT);
        }

        // extra evaluation at (x_last, h_final) for dh_dWh
        {
            float h8[8];
            {
                const float* hb = &hbuf[0][kg * 8];
                float4 a4 = *(const float4*)(hb);
                float4 b4 = *(const float4*)(hb + 4);
                h8[0] = a4.x; h8[1] = a4.y; h8[2] = a4.z; h8[3] = a4.w;
                h8[4] = b4.x; h8[5] = b4.y; h8[6] = b4.z; h8[7] = b4.w;
            }
            float s0 = 0.f, s1 = 0.f, s2 = 0.f, s3 = 0.f;
#pragma unroll
            for (int kk = 0; kk < 8; ++kk) {
                s0 += h8[kk] * wh[0][kk];
                s1 += h8[kk] * wh[1][kk];
                s2 += h8[kk] * wh[2][kk];
                s3 += h8[kk] * wh[3][kk];
            }
            s0 = row_reduce16(s0); s1 = row_reduce16(s1);
            s2 = row_reduce16(s2); s3 = row_reduce16(s3);
            float pre = (mm == 0) ? (xwv4.x + s0) : (mm == 1) ? (xwv4.y + s1)
                      : (mm == 2) ? (xwv4.z + s2) : (xwv4.w + s3);   // xwv4 == xw[b,255]
            float a, dval;
            gelu_pair(pre, a, dval);
            if (wlane) {
                __hip_atomic_store(&wdF[b * 128 + iw], dval, __ATOMIC_RELAXED, __HIP_MEMORY_SCOPE_AGENT);
                abuf[iw] = a;
            }
            __syncthreads();
            float a8[8];
            {
                const float* ab = &abuf[kg * 8];
                float4 a4 = *(const float4*)(ab);
                float4 b4 = *(const float4*)(ab + 4);
                a8[0] = a4.x; a8[1] = a4.y; a8[2] = a4.z; a8[3] = a4.w;
                a8[4] = b4.x; a8[5] = b4.y; a8[6] = b4.z; a8[7] = b4.w;
            }
            float r0 = 0.f, r1 = 0.f, r2 = 0.f, r3 = 0.f;
#pragma unroll
            for (int kk = 0; kk < 8; ++kk) {
                r0 += a8[kk] * wgc[0][kk];
                r1 += a8[kk] * wgc[1][kk];
                r2 += a8[kk] * wgc[2][kk];
                r3 += a8[kk] * wgc[3][kk];
            }
            r0 = row_reduce16(r0); r1 = row_reduce16(r1);
            r2 = row_reduce16(r2); r3 = row_reduce16(r3);
            float r = (mm == 0) ? r0 : (mm == 1) ? r1 : (mm == 2) ? r2 : r3;
            float g = 1.0f / (1.0f + __expf(-r));
            if (wlane)
                __hip_atomic_store(&wuF[b * 128 + iw], (hfin - 1.0f) * g * (1.0f - g),
                                   __ATOMIC_RELAXED, __HIP_MEMORY_SCOPE_AGENT);
        }
        __syncthreads();                                       // drain final agent stores
        if (tid == 0)
            __hip_atomic_fetch_add(&ctrl[16], 1u, __ATOMIC_RELAXED, __HIP_MEMORY_SCOPE_AGENT);
        // fall through: scan blocks join the worker pool
    }

    // ================= worker loop (dynamic tickets; no consumer fences) =================
    const int lane = tid & 63;
    for (;;) {
        if (tid == 0)
            sh_u = __hip_atomic_fetch_add(&ctrl[64], 1u, __ATOMIC_RELAXED, __HIP_MEMORY_SCOPE_AGENT);
        __syncthreads();
        unsigned u = sh_u;
        if (u >= NTICK_TOTAL) break;

        if (u < NTICK_JAC) {
            // ---- jac tile ----
            int rb = (int)(u >> 7), cb = (int)(u & 127u);
            int fidx = (4 * rb + 3) >> 4;
            if (tid == 0) {
                while (__hip_atomic_load(&ctrl[fidx], __ATOMIC_RELAXED, __HIP_MEMORY_SCOPE_AGENT) < 32u)
                    __builtin_amdgcn_s_sleep(32);
            }
            __syncthreads();
            // no acquire fence: regions first-touched after flag; L2 clean at dispatch start.

            const short* Ag = Abf + (long)rb * (128 * 128);
            const short* Bg = PT + (long)cb * (128 * 128);

            int w = tid >> 6;            // wave 0..7
            int wr = w >> 2;             // row half (64 rows)
            int wcol = w & 3;            // col quarter (32 cols)
            int lrow = lane & 15;
            int quad = lane >> 4;

            long rowbase = (long)rb * 128;
            float ci[4][4], gi[4][4];
#pragma unroll
            for (int p = 0; p < 4; ++p) {
                int trow0 = wr * 64 + p * 16 + quad * 4;
#pragma unroll
                for (int reg = 0; reg < 4; ++reg) {
                    long row = rowbase + trow0 + reg;
                    ci[p][reg] = wc[row * 128 + cb];
                    gi[p][reg] = wgv[row * 128 + cb];
                }
            }

            frag_cd acc[4][2];
#pragma unroll
            for (int p = 0; p < 4; ++p)
#pragma unroll
                for (int q = 0; q < 2; ++q) {
                    acc[p][q][0] = 0.f; acc[p][q][1] = 0.f; acc[p][q][2] = 0.f; acc[p][q][3] = 0.f;
                }

#pragma unroll
            for (int kk = 0; kk < 4; ++kk) {
                int ko8 = (kk * 4 + quad) * 8;
                frag_ab af[4], bf2[2];
#pragma unroll
                for (int p = 0; p < 4; ++p) {
                    int r = wr * 64 + p * 16 + lrow;
                    af[p] = *(const frag_ab*)(Ag + r * 128 + ko8);
                }
#pragma unroll
                for (int q = 0; q < 2; ++q) {
                    int n = wcol * 32 + q * 16 + lrow;
                    bf2[q] = *(const frag_ab*)(Bg + n * 128 + ko8);
                }
#pragma unroll
                for (int p = 0; p < 4; ++p)
#pragma unroll
                    for (int q = 0; q < 2; ++q)
                        acc[p][q] = __builtin_amdgcn_mfma_f32_16x16x32_bf16(af[p], bf2[q], acc[p][q], 0, 0, 0);
            }

            // epilogue: scale+diag -> LDS stage -> nt float4 stores
#pragma unroll
            for (int p0 = 0; p0 < 4; p0 += 2) {
                if (p0) __syncthreads();
#pragma unroll
                for (int dp = 0; dp < 2; ++dp) {
                    int p = p0 + dp;
#pragma unroll
                    for (int reg = 0; reg < 4; ++reg) {
                        int lr = wr * 32 + dp * 16 + quad * 4 + reg;   // 0..63
                        float cval = ci[p][reg], gval = gi[p][reg];
#pragma unroll
                        for (int q = 0; q < 2; ++q) {
                            int tcol = wcol * 32 + q * 16 + lrow;
                            float v = cval * acc[p][q][reg];
                            if (tcol == cb) v += gval;
                            cstage[lr * 132 + tcol] = v;
                        }
                    }
                }
                __syncthreads();
                int col4 = (tid & 31) * 4;
                int rgp = tid >> 5;                  // 0..15, 4 rows each
#pragma unroll
                for (int rr = 0; rr < 4; ++rr) {
                    int lr = rgp * 4 + rr;           // 0..63
                    int grow = (lr < 32) ? (p0 * 16 + lr) : (64 + p0 * 16 + (lr - 32));
                    frag_cd v4 = *(const frag_cd*)&cstage[lr * 132 + col4];
                    __builtin_nontemporal_store(
                        v4, (frag_cd*)(out + JACOFF + (rowbase + grow) * 16384 + (long)cb * 128 + col4));
                }
            }
        } else {
            // ---- dhdw pair: needs full scan ----
            if (tid == 0) {
                while (__hip_atomic_load(&ctrl[16], __ATOMIC_RELAXED, __HIP_MEMORY_SCOPE_AGENT) < 32u)
                    __builtin_amdgcn_s_sleep(32);
            }
            __syncthreads();

            int v = (int)(u - NTICK_JAC);        // 0..2047
            int half = tid >> 8, t2 = tid & 255;
            int gu = v * 2 + half;               // unit = b*128 + i
            int b = gu >> 7, ii = gu & 127;
            if (t2 < 128) {
                hs2[half][t2] = whF[b * 128 + t2];
                ds2[half][t2] = wdF[b * 128 + t2];
            }
            __syncthreads();
            float u_ = wuF[b * 128 + ii];
            int q0 = (t2 & 31) * 4, p0 = (t2 >> 5) * 16;
            float w0 = u_ * ds2[half][q0 + 0] * Wgate[(q0 + 0) * 128 + ii];
            float w1 = u_ * ds2[half][q0 + 1] * Wgate[(q0 + 1) * 128 + ii];
            float w2 = u_ * ds2[half][q0 + 2] * Wgate[(q0 + 2) * 128 + ii];
            float w3 = u_ * ds2[half][q0 + 3] * Wgate[(q0 + 3) * 128 + ii];
            float* dst = out + DHWOFF + (long)gu * 16384;
#pragma unroll
            for (int pp = 0; pp < 16; ++pp) {
                float hp = hs2[half][p0 + pp];
                frag_cd v4; v4[0] = hp * w0; v4[1] = hp * w1; v4[2] = hp * w2; v4[3] = hp * w3;
                __builtin_nontemporal_store(v4, (frag_cd*)(dst + (p0 + pp) * 128 + q0));
            }
        }
        __syncthreads();   // protect sh_u / cstage / hs2 reuse before next ticket
    }
}

extern "C" void kernel_launch(void* const* d_in, const int* in_sizes, int n_in,
                              void* d_out, int out_size, void* d_ws, size_t ws_size,
                              hipStream_t stream)
{
    (void)in_sizes; (void)n_in; (void)out_size; (void)ws_size;
    const float* x     = (const float*)d_in[0];
    const float* h0    = (const float*)d_in[1];
    const float* Wx    = (const float*)d_in[2];
    const float* Wgate = (const float*)d_in[3];
    const float* Wh    = (const float*)d_in[4];
    float* out = (float*)d_out;
    float* ws  = (float*)d_ws;

    // workspace layout (floats), ~19.05 MB
    float* xw  = ws;                         // 1048576
    float* whT = ws + 1048576;               // 16384
    float* wgT = ws + 1064960;               // 16384
    float* wgv = ws + 1081344;               // 1048576
    float* wc  = ws + 2129920;               // 1048576
    float* wdF = ws + 3178496;               // 4096
    float* wuF = ws + 3182592;               // 4096
    float* whF = ws + 3186688;               // 4096
    short* Abf = (short*)(ws + 3190784);     // 1048576 bf16
    short* PT  = (short*)(ws + 3715072);     // 2097152 bf16
    unsigned* ctrl = (unsigned*)(ws + 4763648); // 128 uints

    prep_kernel<<<5249, 256, 0, stream>>>(Wh, Wgate, x, Wx, whT, wgT, xw, PT, ctrl);
    // 52 KB dynamic LDS pad: ~37KB static + 52KB ~= 89KB -> guaranteed 1 block/CU.
    fused_kernel<<<256, 512, 53248, stream>>>(xw, h0, whT, wgT, Wgate, out,
                                              Abf, wgv, wc, wdF, wuF, whF, PT, ctrl);
}

// Round 10
// 1005.590 us; speedup vs baseline: 1.0059x; 1.0059x over previous
//
#include <hip/hip_runtime.h>

// Problem constants: B=32, T=256, IN=64, D=128
// Outputs (fp32): h_final[32,128] | y[32,256,128] | jacs[256,32,128,128] | dh_dWh[32,128,128,128]
// out offsets: 0, 4096, 1052672, 135270400  (total 202379264)
//
// Round 10: XCD isolation for the scan. r8/r9 showed the fused kernel = 462 us
// vs scan-standalone 216 + tail ~50: the serial scan runs ~1.9x slower under
// worker load. r9 killed the barrier-drain theory (counted vmcnt: neutral).
// Remaining mechanism: scan blocks share XCD L2s with 28 streaming worker CUs
// each -> xw loads / y write-backs miss to a congested LLC on the serial
// dependency chain. Fix: scan role = blocks with blockIdx&7==0 (all land on
// XCD 0 by the %8 round-robin [m09]); workers = XCDs 1-7 (224 CUs, unchanged).
// XCD0's private 4MB L2 then holds xw (4MB) exclusively; scan reads become
// ~180cy L2 hits immune to worker traffic. Correctness never depends on the
// mapping: grid=256 @ 1 block/CU (LDS-forced) => all blocks resident.

#define JACOFF 1052672L
#define DHWOFF 135270400L

#define NTICK_JAC   8192u
#define NTICK_TOTAL 10240u   // 8192 jac tiles + 2048 dhdw pairs

typedef __attribute__((ext_vector_type(8))) short frag_ab;   // 8 bf16
typedef __attribute__((ext_vector_type(4))) float frag_cd;   // 4 fp32 (native vec: ok for nt store)

__device__ __forceinline__ short f2bf(float f) {
    unsigned u = __builtin_bit_cast(unsigned, f);
    unsigned r = (u + 0x7fffu + ((u >> 16) & 1u)) >> 16;     // RNE
    return (short)r;
}

__device__ __forceinline__ void wg_barrier() {
    asm volatile("s_waitcnt lgkmcnt(0)\n\ts_barrier" ::: "memory");
}

// Full reduction across a 16-lane DPP row.
__device__ __forceinline__ float row_reduce16(float x) {
    int t;
    t = __builtin_amdgcn_mov_dpp(__builtin_bit_cast(int, x), 0x128, 0xF, 0xF, true);
    x += __builtin_bit_cast(float, t);
    t = __builtin_amdgcn_mov_dpp(__builtin_bit_cast(int, x), 0x124, 0xF, 0xF, true);
    x += __builtin_bit_cast(float, t);
    t = __builtin_amdgcn_mov_dpp(__builtin_bit_cast(int, x), 0x4E, 0xF, 0xF, true);
    x += __builtin_bit_cast(float, t);
    t = __builtin_amdgcn_mov_dpp(__builtin_bit_cast(int, x), 0xB1, 0xF, 0xF, true);
    x += __builtin_bit_cast(float, t);
    return x;
}

// gelu + gelu' with one fast exp (A&S 7.1.26).
__device__ __forceinline__ void gelu_pair(float pre, float& a, float& dval) {
    const float inv_sqrt2   = 0.70710678118654752f;
    const float inv_sqrt2pi = 0.39894228040143268f;
    float ex2 = __expf(-0.5f * pre * pre);
    float az  = fabsf(pre) * inv_sqrt2;
    float t   = 1.0f / (1.0f + 0.3275911f * az);
    float poly = ((((1.061405429f * t - 1.453152027f) * t + 1.421413741f) * t
                   - 0.284496736f) * t + 0.254829592f) * t;
    float erf_abs = 1.0f - poly * ex2;
    float erf_z = (pre < 0.f) ? -erf_abs : erf_abs;
    float cdf = 0.5f * (1.0f + erf_z);
    a = pre * cdf;
    dval = cdf + pre * inv_sqrt2pi * ex2;
}

// ---------- prep: transposes + xw + PT + ctrl zero ----------
__global__ __launch_bounds__(256) void prep_kernel(
    const float* __restrict__ Wh, const float* __restrict__ Wg,
    const float* __restrict__ x, const float* __restrict__ Wx,
    float* __restrict__ whT, float* __restrict__ wgT, float* __restrict__ xw,
    short* __restrict__ PT, unsigned* __restrict__ ctrl)
{
    int blk = blockIdx.x;
    int tid = threadIdx.x;
    if (blk < 128) {
        int idx = blk * 256 + tid;               // 0..32767
        if (idx < 16384) {                       // WhT[i][k] = Wh[k][i]
            int k = idx >> 7, i = idx & 127;
            whT[i * 128 + k] = Wh[idx];
        } else {                                 // WgT[i][k] = Wgate[k][i]
            int r = idx - 16384;
            int k = r >> 7, i = r & 127;
            wgT[i * 128 + k] = Wg[r];
        }
        return;
    }
    if (blk < 4224) {
        // xw path: 2 (b,t) rows per block
        __shared__ float xs[2][64];
        int sub = tid >> 7;
        int bt = (blk - 128) * 2 + sub;
        int i = tid & 127;
        if (i < 64) xs[sub][i] = x[bt * 64 + i];
        __syncthreads();
        float acc = 0.f;
#pragma unroll
        for (int m = 0; m < 64; ++m)
            acc += xs[sub][m] * Wx[m * 128 + i];
        xw[bt * 128 + i] = acc;
        return;
    }
    if (blk < 5248) {
        // PT[col][k] = bf16(Wgate[k][i] * Wh[j][k]), col = i*128+j. 16 cols/block.
        int c = (blk - 4224) * 16 + (tid >> 4);
        int k0 = (tid & 15) * 8;
        int i = c >> 7, j = c & 127;
        short v[8];
#pragma unroll
        for (int m = 0; m < 8; ++m) {
            float wg = Wg[(k0 + m) * 128 + i];
            float wh = Wh[j * 128 + k0 + m];
            v[m] = f2bf(wg * wh);
        }
        *(frag_ab*)(PT + (long)c * 128 + k0) = *(frag_ab*)v;
        return;
    }
    if (tid < 128) ctrl[tid] = 0u;               // flags[0..16], ticket at [64]
}

// ---------- fused scan + jacmm + dhdw (256 blocks x 512 thr, 1 block/CU) ----------
__global__ __launch_bounds__(512, 1) void fused_kernel(
    const float* __restrict__ xw, const float* __restrict__ h0,
    const float* __restrict__ whT, const float* __restrict__ wgT,
    const float* __restrict__ Wgate,
    float* __restrict__ out,
    short* __restrict__ Abf, float* __restrict__ wgv, float* __restrict__ wc,
    float* __restrict__ wdF, float* __restrict__ wuF, float* __restrict__ whF,
    const short* __restrict__ PT, unsigned* __restrict__ ctrl)
{
    const int tid = threadIdx.x;
    __shared__ float hbuf[2][128];
    __shared__ float abuf[128];
    __shared__ float cstage[64 * 132];           // 33.8 KB (stride 132: 2-way = free)
    __shared__ float hs2[2][128], ds2[2][128];
    __shared__ unsigned sh_u;
    // + 52 KB dynamic pad at launch -> ~89 KB total -> exactly 1 block/CU

    if ((blockIdx.x & 7) == 0) {
        // ================= scan (producer) — all on XCD 0 =================
        const int b = blockIdx.x >> 3;  // 0..31
        const int og = tid >> 4;        // 4 outputs: i = og*4+m
        const int kg = tid & 15;        // 8 k-values: k = kg*8..+7
        const int mm = kg & 3;
        const int iw = og * 4 + kg;
        const bool wlane = (kg < 4);

        float wh[4][8], wgc[4][8];
#pragma unroll
        for (int m = 0; m < 4; ++m) {
            const float* whr = whT + (og * 4 + m) * 128 + kg * 8;
            const float* wgr = wgT + (og * 4 + m) * 128 + kg * 8;
            float4 a4 = *(const float4*)(whr);
            float4 b4 = *(const float4*)(whr + 4);
            wh[m][0] = a4.x; wh[m][1] = a4.y; wh[m][2] = a4.z; wh[m][3] = a4.w;
            wh[m][4] = b4.x; wh[m][5] = b4.y; wh[m][6] = b4.z; wh[m][7] = b4.w;
            float4 c4 = *(const float4*)(wgr);
            float4 d4 = *(const float4*)(wgr + 4);
            wgc[m][0] = c4.x; wgc[m][1] = c4.y; wgc[m][2] = c4.z; wgc[m][3] = c4.w;
            wgc[m][4] = d4.x; wgc[m][5] = d4.y; wgc[m][6] = d4.z; wgc[m][7] = d4.w;
        }
        if (wlane) hbuf[0][iw] = h0[b * 128 + iw];
        __syncthreads();

        float4 xwv4 = *(const float4*)(xw + (b * 256 + 0) * 128 + og * 4);
        float4 xw14 = *(const float4*)(xw + (b * 256 + 1) * 128 + og * 4);

        for (int t = 0; t < 256; ++t) {
            int p = t & 1;
            int tn = (t < 254) ? t + 2 : 255;
            float4 xw24 = *(const float4*)(xw + (b * 256 + tn) * 128 + og * 4);

            // phase A
            float h8[8];
            {
                const float* hb = &hbuf[p][kg * 8];
                float4 a4 = *(const float4*)(hb);
                float4 b4 = *(const float4*)(hb + 4);
                h8[0] = a4.x; h8[1] = a4.y; h8[2] = a4.z; h8[3] = a4.w;
                h8[4] = b4.x; h8[5] = b4.y; h8[6] = b4.z; h8[7] = b4.w;
            }
            float s0 = 0.f, s1 = 0.f, s2 = 0.f, s3 = 0.f;
#pragma unroll
            for (int kk = 0; kk < 8; ++kk) {
                s0 += h8[kk] * wh[0][kk];
                s1 += h8[kk] * wh[1][kk];
                s2 += h8[kk] * wh[2][kk];
                s3 += h8[kk] * wh[3][kk];
            }
            s0 = row_reduce16(s0); s1 = row_reduce16(s1);
            s2 = row_reduce16(s2); s3 = row_reduce16(s3);
            float pre = (mm == 0) ? (xwv4.x + s0) : (mm == 1) ? (xwv4.y + s1)
                      : (mm == 2) ? (xwv4.z + s2) : (xwv4.w + s3);
            float a, dval;
            gelu_pair(pre, a, dval);

            long tb = (long)(t * 32 + b) * 128 + iw;
            if (wlane) {
                __hip_atomic_store(&Abf[tb], f2bf(dval), __ATOMIC_RELAXED, __HIP_MEMORY_SCOPE_AGENT);
                abuf[iw] = a;
            }
            wg_barrier();                                      // (1) abuf visible

            // phase B
            float a8[8];
            {
                const float* ab = &abuf[kg * 8];
                float4 a4 = *(const float4*)(ab);
                float4 b4 = *(const float4*)(ab + 4);
                a8[0] = a4.x; a8[1] = a4.y; a8[2] = a4.z; a8[3] = a4.w;
                a8[4] = b4.x; a8[5] = b4.y; a8[6] = b4.z; a8[7] = b4.w;
            }
            float r0 = 0.f, r1 = 0.f, r2 = 0.f, r3 = 0.f;
#pragma unroll
            for (int kk = 0; kk < 8; ++kk) {
                r0 += a8[kk] * wgc[0][kk];
                r1 += a8[kk] * wgc[1][kk];
                r2 += a8[kk] * wgc[2][kk];
                r3 += a8[kk] * wgc[3][kk];
            }
            r0 = row_reduce16(r0); r1 = row_reduce16(r1);
            r2 = row_reduce16(r2); r3 = row_reduce16(r3);
            float r = (mm == 0) ? r0 : (mm == 1) ? r1 : (mm == 2) ? r2 : r3;

            float g = 1.0f / (1.0f + __expf(-r));
            float hp = hbuf[p][og * 4 + mm];
            float c = (hp - 1.0f) * g * (1.0f - g);
            float hn = g * hp + 1.0f - g;
            if (wlane) {
                hbuf[p ^ 1][iw] = hn;
                __hip_atomic_store(&wgv[tb], g, __ATOMIC_RELAXED, __HIP_MEMORY_SCOPE_AGENT);
                __hip_atomic_store(&wc[tb], c, __ATOMIC_RELAXED, __HIP_MEMORY_SCOPE_AGENT);
                out[4096 + (b * 256 + t) * 128 + iw] = hn;     // y
            }
            xwv4 = xw14; xw14 = xw24;

            // Delayed counted-vmcnt publication (r9): at t = 16c+19 all of chunk
            // c's stores are >=4 steps old; vmcnt(16) proves retirement w/o drain.
            if ((t & 15) == 3 && t >= 19) {
                asm volatile("s_waitcnt vmcnt(16)" ::: "memory");
                wg_barrier();                                  // (2) new h visible
                if (tid == 0)
                    __hip_atomic_fetch_add(&ctrl[(t >> 4) - 1], 1u, __ATOMIC_RELAXED, __HIP_MEMORY_SCOPE_AGENT);
            } else {
                wg_barrier();                                  // (2) new h visible
            }
        }

        // full drain once, then publish chunk 15
        __syncthreads();
        if (tid == 0)
            __hip_atomic_fetch_add(&ctrl[15], 1u, __ATOMIC_RELAXED, __HIP_MEMORY_SCOPE_AGENT);

        float hfin = hbuf[0][og * 4 + mm];
        if (wlane) {
            out[b * 128 + iw] = hbuf[0][iw];                   // h_final
            __hip_atomic_store(&whF[b * 128 + iw], hbuf[0][iw], __ATOMIC_RELAXED, __HIP_MEMORY_SCOPE_AGENT);
        }

        // extra evaluation at (x_last, h_final) for dh_dWh
        {
            float h8[8];
            {
                const float* hb = &hbuf[0][kg * 8];
                float4 a4 = *(const float4*)(hb);
                float4 b4 = *(const float4*)(hb + 4);
                h8[0] = a4.x; h8[1] = a4.y; h8[2] = a4.z; h8[3] = a4.w;
                h8[4] = b4.x; h8[5] = b4.y; h8[6] = b4.z; h8[7] = b4.w;
            }
            float s0 = 0.f, s1 = 0.f, s2 = 0.f, s3 = 0.f;
#pragma unroll
            for (int kk = 0; kk < 8; ++kk) {
                s0 += h8[kk] * wh[0][kk];
                s1 += h8[kk] * wh[1][kk];
                s2 += h8[kk] * wh[2][kk];
                s3 += h8[kk] * wh[3][kk];
            }
            s0 = row_reduce16(s0); s1 = row_reduce16(s1);
            s2 = row_reduce16(s2); s3 = row_reduce16(s3);
            float pre = (mm == 0) ? (xwv4.x + s0) : (mm == 1) ? (xwv4.y + s1)
                      : (mm == 2) ? (xwv4.z + s2) : (xwv4.w + s3);   // xwv4 == xw[b,255]
            float a, dval;
            gelu_pair(pre, a, dval);
            if (wlane) {
                __hip_atomic_store(&wdF[b * 128 + iw], dval, __ATOMIC_RELAXED, __HIP_MEMORY_SCOPE_AGENT);
                abuf[iw] = a;
            }
            __syncthreads();
            float a8[8];
            {
                const float* ab = &abuf[kg * 8];
                float4 a4 = *(const float4*)(ab);
                float4 b4 = *(const float4*)(ab + 4);
                a8[0] = a4.x; a8[1] = a4.y; a8[2] = a4.z; a8[3] = a4.w;
                a8[4] = b4.x; a8[5] = b4.y; a8[6] = b4.z; a8[7] = b4.w;
            }
            float r0 = 0.f, r1 = 0.f, r2 = 0.f, r3 = 0.f;
#pragma unroll
            for (int kk = 0; kk < 8; ++kk) {
                r0 += a8[kk] * wgc[0][kk];
                r1 += a8[kk] * wgc[1][kk];
                r2 += a8[kk] * wgc[2][kk];
                r3 += a8[kk] * wgc[3][kk];
            }
            r0 = row_reduce16(r0); r1 = row_reduce16(r1);
            r2 = row_reduce16(r2); r3 = row_reduce16(r3);
            float r = (mm == 0) ? r0 : (mm == 1) ? r1 : (mm == 2) ? r2 : r3;
            float g = 1.0f / (1.0f + __expf(-r));
            if (wlane)
                __hip_atomic_store(&wuF[b * 128 + iw], (hfin - 1.0f) * g * (1.0f - g),
                                   __ATOMIC_RELAXED, __HIP_MEMORY_SCOPE_AGENT);
        }
        __syncthreads();                                       // drain final agent stores
        if (tid == 0)
            __hip_atomic_fetch_add(&ctrl[16], 1u, __ATOMIC_RELAXED, __HIP_MEMORY_SCOPE_AGENT);
        // fall through: scan blocks join the worker pool
    }

    // ================= worker loop (dynamic tickets; no consumer fences) =================
    const int lane = tid & 63;
    for (;;) {
        if (tid == 0)
            sh_u = __hip_atomic_fetch_add(&ctrl[64], 1u, __ATOMIC_RELAXED, __HIP_MEMORY_SCOPE_AGENT);
        __syncthreads();
        unsigned u = sh_u;
        if (u >= NTICK_TOTAL) break;

        if (u < NTICK_JAC) {
            // ---- jac tile ----
            int rb = (int)(u >> 7), cb = (int)(u & 127u);
            int fidx = (4 * rb + 3) >> 4;
            if (tid == 0) {
                while (__hip_atomic_load(&ctrl[fidx], __ATOMIC_RELAXED, __HIP_MEMORY_SCOPE_AGENT) < 32u)
                    __builtin_amdgcn_s_sleep(32);
            }
            __syncthreads();
            // no acquire fence: regions first-touched after flag; L2 clean at dispatch start.

            const short* Ag = Abf + (long)rb * (128 * 128);
            const short* Bg = PT + (long)cb * (128 * 128);

            int w = tid >> 6;            // wave 0..7
            int wr = w >> 2;             // row half (64 rows)
            int wcol = w & 3;            // col quarter (32 cols)
            int lrow = lane & 15;
            int quad = lane >> 4;

            long rowbase = (long)rb * 128;
            float ci[4][4], gi[4][4];
#pragma unroll
            for (int p = 0; p < 4; ++p) {
                int trow0 = wr * 64 + p * 16 + quad * 4;
#pragma unroll
                for (int reg = 0; reg < 4; ++reg) {
                    long row = rowbase + trow0 + reg;
                    ci[p][reg] = wc[row * 128 + cb];
                    gi[p][reg] = wgv[row * 128 + cb];
                }
            }

            frag_cd acc[4][2];
#pragma unroll
            for (int p = 0; p < 4; ++p)
#pragma unroll
                for (int q = 0; q < 2; ++q) {
                    acc[p][q][0] = 0.f; acc[p][q][1] = 0.f; acc[p][q][2] = 0.f; acc[p][q][3] = 0.f;
                }

#pragma unroll
            for (int kk = 0; kk < 4; ++kk) {
                int ko8 = (kk * 4 + quad) * 8;
                frag_ab af[4], bf2[2];
#pragma unroll
                for (int p = 0; p < 4; ++p) {
                    int r = wr * 64 + p * 16 + lrow;
                    af[p] = *(const frag_ab*)(Ag + r * 128 + ko8);
                }
#pragma unroll
                for (int q = 0; q < 2; ++q) {
                    int n = wcol * 32 + q * 16 + lrow;
                    bf2[q] = *(const frag_ab*)(Bg + n * 128 + ko8);
                }
#pragma unroll
                for (int p = 0; p < 4; ++p)
#pragma unroll
                    for (int q = 0; q < 2; ++q)
                        acc[p][q] = __builtin_amdgcn_mfma_f32_16x16x32_bf16(af[p], bf2[q], acc[p][q], 0, 0, 0);
            }

            // epilogue: scale+diag -> LDS stage -> nt float4 stores
#pragma unroll
            for (int p0 = 0; p0 < 4; p0 += 2) {
                if (p0) __syncthreads();
#pragma unroll
                for (int dp = 0; dp < 2; ++dp) {
                    int p = p0 + dp;
#pragma unroll
                    for (int reg = 0; reg < 4; ++reg) {
                        int lr = wr * 32 + dp * 16 + quad * 4 + reg;   // 0..63
                        float cval = ci[p][reg], gval = gi[p][reg];
#pragma unroll
                        for (int q = 0; q < 2; ++q) {
                            int tcol = wcol * 32 + q * 16 + lrow;
                            float v = cval * acc[p][q][reg];
                            if (tcol == cb) v += gval;
                            cstage[lr * 132 + tcol] = v;
                        }
                    }
                }
                __syncthreads();
                int col4 = (tid & 31) * 4;
                int rgp = tid >> 5;                  // 0..15, 4 rows each
#pragma unroll
                for (int rr = 0; rr < 4; ++rr) {
                    int lr = rgp * 4 + rr;           // 0..63
                    int grow = (lr < 32) ? (p0 * 16 + lr) : (64 + p0 * 16 + (lr - 32));
                    frag_cd v4 = *(const frag_cd*)&cstage[lr * 132 + col4];
                    __builtin_nontemporal_store(
                        v4, (frag_cd*)(out + JACOFF + (rowbase + grow) * 16384 + (long)cb * 128 + col4));
                }
            }
        } else {
            // ---- dhdw pair: needs full scan ----
            if (tid == 0) {
                while (__hip_atomic_load(&ctrl[16], __ATOMIC_RELAXED, __HIP_MEMORY_SCOPE_AGENT) < 32u)
                    __builtin_amdgcn_s_sleep(32);
            }
            __syncthreads();

            int v = (int)(u - NTICK_JAC);        // 0..2047
            int half = tid >> 8, t2 = tid & 255;
            int gu = v * 2 + half;               // unit = b*128 + i
            int b = gu >> 7, ii = gu & 127;
            if (t2 < 128) {
                hs2[half][t2] = whF[b * 128 + t2];
                ds2[half][t2] = wdF[b * 128 + t2];
            }
            __syncthreads();
            float u_ = wuF[b * 128 + ii];
            int q0 = (t2 & 31) * 4, p0 = (t2 >> 5) * 16;
            float w0 = u_ * ds2[half][q0 + 0] * Wgate[(q0 + 0) * 128 + ii];
            float w1 = u_ * ds2[half][q0 + 1] * Wgate[(q0 + 1) * 128 + ii];
            float w2 = u_ * ds2[half][q0 + 2] * Wgate[(q0 + 2) * 128 + ii];
            float w3 = u_ * ds2[half][q0 + 3] * Wgate[(q0 + 3) * 128 + ii];
            float* dst = out + DHWOFF + (long)gu * 16384;
#pragma unroll
            for (int pp = 0; pp < 16; ++pp) {
                float hp = hs2[half][p0 + pp];
                frag_cd v4; v4[0] = hp * w0; v4[1] = hp * w1; v4[2] = hp * w2; v4[3] = hp * w3;
                __builtin_nontemporal_store(v4, (frag_cd*)(dst + (p0 + pp) * 128 + q0));
            }
        }
        __syncthreads();   // protect sh_u / cstage / hs2 reuse before next ticket
    }
}

extern "C" void kernel_launch(void* const* d_in, const int* in_sizes, int n_in,
                              void* d_out, int out_size, void* d_ws, size_t ws_size,
                              hipStream_t stream)
{
    (void)in_sizes; (void)n_in; (void)out_size; (void)ws_size;
    const float* x     = (const float*)d_in[0];
    const float* h0    = (const float*)d_in[1];
    const float* Wx    = (const float*)d_in[2];
    const float* Wgate = (const float*)d_in[3];
    const float* Wh    = (const float*)d_in[4];
    float* out = (float*)d_out;
    float* ws  = (float*)d_ws;

    // workspace layout (floats), ~19.05 MB
    float* xw  = ws;                         // 1048576
    float* whT = ws + 1048576;               // 16384
    float* wgT = ws + 1064960;               // 16384
    float* wgv = ws + 1081344;               // 1048576
    float* wc  = ws + 2129920;               // 1048576
    float* wdF = ws + 3178496;               // 4096
    float* wuF = ws + 3182592;               // 4096
    float* whF = ws + 3186688;               // 4096
    short* Abf = (short*)(ws + 3190784);     // 1048576 bf16
    short* PT  = (short*)(ws + 3715072);     // 2097152 bf16
    unsigned* ctrl = (unsigned*)(ws + 4763648); // 128 uints

    prep_kernel<<<5249, 256, 0, stream>>>(Wh, Wgate, x, Wx, whT, wgT, xw, PT, ctrl);
    // 52 KB dynamic LDS pad: ~37KB static + 52KB ~= 89KB -> guaranteed 1 block/CU.
    fused_kernel<<<256, 512, 53248, stream>>>(xw, h0, whT, wgT, Wgate, out,
                                              Abf, wgv, wc, wdF, wuF, whF, PT, ctrl);
}